// Round 15
// baseline (524.250 us; speedup 1.0000x reference)
//
#include <hip/hip_runtime.h>
#include <stdint.h>

typedef _Float16 h8_t __attribute__((ext_vector_type(8)));
typedef _Float16 h4_t __attribute__((ext_vector_type(4)));
typedef float f32x4 __attribute__((ext_vector_type(4)));

union H8 { h8_t v; uint32_t u[4]; _Float16 h[8]; };
union H4 { h4_t v; uint32_t u[2]; _Float16 h[4]; };

struct TrueT  { static constexpr bool value = true;  };
struct FalseT { static constexpr bool value = false; };

// ---------- workspace layout (doubles) ----------
// [0,288) binacc[3][32][3] ; [288,480) stats[3][32][2] (sum,sumsq)

__global__ void zero_ws(double* wsd) {
    int i = threadIdx.x;
    if (i < 480)
        __hip_atomic_store(&wsd[i], 0.0, __ATOMIC_RELAXED, __HIP_MEMORY_SCOPE_AGENT);
}

// ---------- FFT + global-stats kernel: 2 independent 512-pt FFTs per block ----------
__global__ __launch_bounds__(512) void fft_stats(const float* __restrict__ noisy,
                                                 const float* __restrict__ base,
                                                 const float* __restrict__ mem,
                                                 double* __restrict__ binacc,
                                                 double* __restrict__ stats) {
    int bid = blockIdx.x;
    int tid = threadIdx.x;
    int f   = tid >> 8;                    // which FFT half-block owns
    int t   = tid & 255;
    int rp  = ((bid & 127) << 1) | f;      // row-pair 0..255
    int b   = (bid >> 7) & 31;
    int iid = bid >> 12;                   // 0..2
    const float* x = (iid == 0) ? noisy : (iid == 1) ? base : mem;
    const float* rowA = x + (((size_t)b << 9) + (rp << 1)) * 512;
    const float* rowB = rowA + 512;

    __shared__ float re[1024], im[1024];
    __shared__ float2 tw[256];
    __shared__ float sbins[3];
    __shared__ float swsum[8], swsq[8];
    const int fb = f << 9;

    if (tid < 256) {
        float ang = -6.2831853071795864769f * (float)tid * (1.f / 512.f);
        float sn, cs;
        __sincosf(ang, &sn, &cs);
        tw[tid] = make_float2(cs, sn);
    }

    float a0 = rowA[t], a1 = rowA[t + 256];
    float b0 = rowB[t], b1 = rowB[t + 256];

    int r0 = __brev((unsigned)t) >> 23;
    int r1 = __brev((unsigned)(t + 256)) >> 23;
    re[fb + r0] = a0; im[fb + r0] = b0;
    re[fb + r1] = a1; im[fb + r1] = b1;

    float ps = a0 + a1 + b0 + b1;
    float pq = a0 * a0 + a1 * a1 + b0 * b0 + b1 * b1;
    #pragma unroll
    for (int off = 32; off > 0; off >>= 1) {
        ps += __shfl_down(ps, off);
        pq += __shfl_down(pq, off);
    }
    if ((tid & 63) == 0) { swsum[tid >> 6] = ps; swsq[tid >> 6] = pq; }
    if (tid < 3) sbins[tid] = 0.f;
    __syncthreads();

    for (int s = 1; s <= 9; ++s) {
        int h = 1 << (s - 1);
        int pos = t & (h - 1);
        int grp = t >> (s - 1);
        int i0 = fb + (grp << s) + pos;
        int i1 = i0 + h;
        float2 w = tw[pos << (9 - s)];
        float cs = w.x, sn = w.y;
        float xr = re[i1], xi = im[i1];
        float tr = xr * cs - xi * sn;
        float ti = xr * sn + xi * cs;
        float ur = re[i0], ui = im[i0];
        re[i1] = ur - tr; im[i1] = ui - ti;
        re[i0] = ur + tr; im[i0] = ui + ti;
        __syncthreads();
    }

    for (int fq = t; fq <= 256; fq += 256) {
        int nf = (512 - fq) & 511;
        float zr = re[fb + fq], zi = im[fb + fq];
        float yr = re[fb + nf], yi = im[fb + nf];
        float ar = 0.5f * (zr + yr), ai = 0.5f * (zi - yi);
        float br = 0.5f * (zi + yi), bi = -0.5f * (zr - yr);
        float pw = ar * ar + ai * ai + br * br + bi * bi;
        int bin = (fq < 85) ? 0 : ((fq < 170) ? 1 : 2);
        atomicAdd(&sbins[bin], pw);
    }
    __syncthreads();
    if (tid < 3) atomicAdd(&binacc[(iid * 32 + b) * 3 + tid], (double)sbins[tid]);
    if (tid == 0) {
        float s8 = 0.f, q8 = 0.f;
        #pragma unroll
        for (int i = 0; i < 8; ++i) { s8 += swsum[i]; q8 += swsq[i]; }
        atomicAdd(&stats[(iid * 32 + b) * 2 + 0], (double)s8);
        atomicAdd(&stats[(iid * 32 + b) * 2 + 1], (double)q8);
    }
}

// ---------- fused MLP + MFMA conv1+conv2+conv3 + epilogue ----------
// 32x32 tile, 256 threads (4 waves), 2 blocks/CU.
// LDS split into ci-half arrays: pixel stride 8 f16 = 16B = 4 words -> 16-lane
// group reads are 2-way bank aliased (free) instead of 4-way. Read half = g&1,
// write half = g>>1 (+ (g&1)*4 offset) per the MFMA fragment mapping.
// No pads/gaps: every reachable address is conv-written or staged data.
__global__ __launch_bounds__(256, 2) void conv_fused(
    const float* __restrict__ noisy, const float* __restrict__ base,
    const float* __restrict__ w1, const float* __restrict__ b1,
    const float* __restrict__ w2, const float* __restrict__ b2,
    const float* __restrict__ w3, const float* __restrict__ b3,
    const double* __restrict__ binacc, const double* __restrict__ stats,
    const float* __restrict__ mw1, const float* __restrict__ mb1,
    const float* __restrict__ mw2, const float* __restrict__ mb2,
    float* __restrict__ out) {

    __shared__ _Float16 sH1lo[36 * 36 * 8], sH1hi[36 * 36 * 8];   // 20736 B each... (10368 f16 ea)
    __shared__ _Float16 sH2lo[34 * 34 * 8], sH2hi[34 * 34 * 8];   // 9248 f16 ea
    __shared__ float sMLP[18];               // hid[16], gamma, beta
    _Float16* sIn = sH2lo;                   // overlay [38][40][2] = 3040 f16 <= 9248

    const int tid = threadIdx.x;
    const int bid = blockIdx.x;
    const int bx = bid & 15, by = (bid >> 4) & 15, b = bid >> 8;
    const int oy0 = by * 32, ox0 = bx * 32;
    const int l = tid & 63, wave = tid >> 6;
    const int g = l >> 4, c15 = l & 15;
    const int t1 = g >> 1, e8 = (g & 1) << 3;
    const bool interior = ((unsigned)(bx - 1) < 14u) && ((unsigned)(by - 1) < 14u);

    _Float16* h1r = (g & 1) ? sH1hi : sH1lo;    // conv2 B-read half
    _Float16* h2r = (g & 1) ? sH2hi : sH2lo;    // conv3 B-read half
    _Float16* h1w = (g >> 1) ? sH1hi : sH1lo;   // conv1 D-write half
    _Float16* h2w = (g >> 1) ? sH2hi : sH2lo;   // conv2 D-write half
    const int wco = (g & 1) * 4;                // write offset within half

    // ---- MLP phase A: threads 0..15 each compute one hidden unit ----
    if (tid < 16) {
        float feats[15];
        const double N = 262144.0;
        #pragma unroll
        for (int i = 0; i < 3; ++i) {
            const double* sp = &stats[(i * 32 + b) * 2];
            double s = __hip_atomic_load(&sp[0], __ATOMIC_RELAXED, __HIP_MEMORY_SCOPE_AGENT);
            double q = __hip_atomic_load(&sp[1], __ATOMIC_RELAXED, __HIP_MEMORY_SCOPE_AGENT);
            double mean = s / N;
            double var = (q - s * s / N) / (N - 1.0);
            feats[2 * i]     = (float)mean;
            feats[2 * i + 1] = sqrtf(fmaxf((float)var, 0.f));
        }
        const double cnt[3] = {85.0, 85.0, 87.0};
        #pragma unroll
        for (int i = 0; i < 3; ++i) {
            float fv[3]; float m = 0.f;
            #pragma unroll
            for (int k = 0; k < 3; ++k) {
                const double* bp = &binacc[(i * 32 + b) * 3 + k];
                double bv = __hip_atomic_load(bp, __ATOMIC_RELAXED, __HIP_MEMORY_SCOPE_AGENT);
                fv[k] = log1pf((float)(bv / (512.0 * cnt[k])));
                m += fv[k];
            }
            m = m * (1.f / 3.f);
            #pragma unroll
            for (int k = 0; k < 3; ++k) feats[6 + i * 3 + k] = fv[k] / (m + 1e-6f);
        }
        float a = mb1[tid];
        #pragma unroll
        for (int j = 0; j < 15; ++j) a += mw1[tid * 15 + j] * feats[j];
        sMLP[tid] = fmaxf(a, 0.f);
    }

    // ---- weight fragments (A operands), VGPR-resident ----
    H8 wf1; H8 wf2[5]; H8 wf3[5];
    #pragma unroll
    for (int i = 0; i < 8; ++i) {
        int k = 8 * g + i;
        float wv = 0.f;
        if (k < 18) wv = w1[c15 * 18 + (k & 1) * 9 + (k >> 1)];
        wf1.h[i] = (_Float16)wv;
    }
    #pragma unroll
    for (int c = 0; c < 4; ++c) {
        int tap = 2 * c + t1;
        #pragma unroll
        for (int i = 0; i < 8; ++i) {
            int ci = e8 + i;
            wf2[c].h[i] = (_Float16)w2[c15 * 144 + ci * 9 + tap];
            float w3v = 0.f;
            if (c15 == 0) w3v = w3[ci * 9 + tap];
            wf3[c].h[i] = (_Float16)w3v;
        }
    }
    #pragma unroll
    for (int i = 0; i < 8; ++i) {
        float w2v = 0.f, w3v = 0.f;
        if (g < 2) {
            int ci = (g << 3) + i;
            w2v = w2[c15 * 144 + ci * 9 + 8];
            if (c15 == 0) w3v = w3[ci * 9 + 8];
        }
        wf2[4].h[i] = (_Float16)w2v;
        wf3[4].h[i] = (_Float16)w3v;
    }

    // ---- precomputed per-lane LDS offsets (loop-invariant) ----
    int offIn[4], off2[5], off3[5];
    #pragma unroll
    for (int j = 0; j < 4; ++j) {
        int tap = 4 * g + j;
        int dy = (tap * 171) >> 9;
        int dx = tap - 3 * dy;
        offIn[j] = (tap < 9) ? ((dy * 40 + dx) * 2) : 0;   // invalid -> 0 (A rows are zero)
    }
    #pragma unroll
    for (int c = 0; c < 5; ++c) {
        int tap = (c < 4) ? (2 * c + t1) : 8;
        int dy = (tap * 171) >> 9;
        int dx = tap - 3 * dy;
        off2[c] = (dy * 36 + dx) * 8;    // within-half element offset
        off3[c] = (dy * 34 + dx) * 8;
    }

    // ---- main body (templated on interior fast path) ----
    auto body = [&](auto tag) {
        constexpr bool INT = decltype(tag)::value;

        // stage input tile f16 [38][40][2] (halo 3)
        {
            const float* nB = noisy + ((size_t)b << 18);
            const float* bB = base + ((size_t)b << 18);
            for (int idx = tid; idx < 38 * 38; idx += 256) {
                unsigned iy = (unsigned)idx / 38u, ix = (unsigned)idx - iy * 38u;
                int gy = oy0 + (int)iy - 3, gx = ox0 + (int)ix - 3;
                float vn, vb;
                if constexpr (INT) {
                    int o = (gy << 9) + gx;
                    vn = nB[o]; vb = bB[o];
                } else {
                    vn = 0.f; vb = 0.f;
                    if ((unsigned)gy < 512u && (unsigned)gx < 512u) {
                        int o = (gy << 9) + gx;
                        vn = nB[o]; vb = bB[o];
                    }
                }
                union { uint32_t u; _Float16 h[2]; } pk;
                pk.h[0] = (_Float16)vn; pk.h[1] = (_Float16)vb;
                *(uint32_t*)&sIn[((int)iy * 40 + (int)ix) * 2] = pk.u;
            }
        }
        __syncthreads();

        // conv1: 2->16, 36x36 out — fixed 21 iterations, fully unrolled
        {
            f32x4 binit;
            #pragma unroll
            for (int i = 0; i < 4; ++i) binit[i] = b1[4 * g + i];
            #pragma unroll
            for (int it = 0; it < 21; ++it) {
                int t = wave + 4 * it;
                unsigned p = (unsigned)(t * 16 + c15);
                bool valid = p < 1296u;
                if (p > 1295u) p = 1295u;
                unsigned y1 = p / 36u, x1 = p - y1 * 36u;
                int baseIn = (y1 * 40 + x1) * 2;
                H8 bf;
                #pragma unroll
                for (int j = 0; j < 4; ++j)
                    bf.u[j] = *(const uint32_t*)&sIn[baseIn + offIn[j]];
                f32x4 acc = __builtin_amdgcn_mfma_f32_16x16x32_f16(wf1.v, bf.v, binit, 0, 0, 0);
                H4 st;
                if constexpr (INT) {
                    #pragma unroll
                    for (int i = 0; i < 4; ++i) st.h[i] = (_Float16)fmaxf(acc[i], 0.f);
                } else {
                    int gy = oy0 + (int)y1 - 2, gx = ox0 + (int)x1 - 2;
                    bool inimg = ((unsigned)gy < 512u) && ((unsigned)gx < 512u);
                    #pragma unroll
                    for (int i = 0; i < 4; ++i)
                        st.h[i] = inimg ? (_Float16)fmaxf(acc[i], 0.f) : (_Float16)0.f;
                }
                if (valid)
                    *(h4_t*)&h1w[p * 8 + wco] = st.v;
            }
        }
        __syncthreads();

        // MLP phase B: thread 0 finishes gamma/beta
        if (tid == 0) {
            float h0 = mb2[0], h1 = mb2[1];
            #pragma unroll
            for (int j = 0; j < 16; ++j) { h0 += mw2[j] * sMLP[j]; h1 += mw2[16 + j] * sMLP[j]; }
            sMLP[16] = 1.f / (1.f + expf(-h0));
            sMLP[17] = 0.1f * tanhf(h1);
        }

        // conv2: 16->16, 34x34 out — fixed 10 dual-tile iterations, fully unrolled
        {
            f32x4 binit;
            #pragma unroll
            for (int i = 0; i < 4; ++i) binit[i] = b2[4 * g + i];
            #pragma unroll
            for (int it = 0; it < 10; ++it) {
                int t = wave + 8 * it;
                int tB = t + 4;
                unsigned pA = (unsigned)(t * 16 + c15);  if (pA > 1155u) pA = 1155u;
                unsigned pB = (unsigned)(tB * 16 + c15); if (pB > 1155u) pB = 1155u;
                unsigned yA = pA / 34u, xA = pA - yA * 34u;
                unsigned yB = pB / 34u, xB = pB - yB * 34u;
                int baseA = (int)(yA * 36 + xA) * 8;
                int baseB = (int)(yB * 36 + xB) * 8;
                f32x4 accA = binit, accB = binit;
                #pragma unroll
                for (int c = 0; c < 5; ++c) {
                    H8 bfA, bfB;
                    bfA.v = *(const h8_t*)&h1r[baseA + off2[c]];
                    bfB.v = *(const h8_t*)&h1r[baseB + off2[c]];
                    accA = __builtin_amdgcn_mfma_f32_16x16x32_f16(wf2[c].v, bfA.v, accA, 0, 0, 0);
                    accB = __builtin_amdgcn_mfma_f32_16x16x32_f16(wf2[c].v, bfB.v, accB, 0, 0, 0);
                }
                if ((unsigned)(t * 16 + c15) < 1156u) {
                    H4 st;
                    if constexpr (INT) {
                        #pragma unroll
                        for (int i = 0; i < 4; ++i) st.h[i] = (_Float16)fmaxf(accA[i], 0.f);
                    } else {
                        int gy = oy0 + (int)yA - 1, gx = ox0 + (int)xA - 1;
                        bool inimg = ((unsigned)gy < 512u) && ((unsigned)gx < 512u);
                        #pragma unroll
                        for (int i = 0; i < 4; ++i)
                            st.h[i] = inimg ? (_Float16)fmaxf(accA[i], 0.f) : (_Float16)0.f;
                    }
                    *(h4_t*)&h2w[(yA * 34 + xA) * 8 + wco] = st.v;
                }
                if ((unsigned)(tB * 16 + c15) < 1156u) {
                    H4 st;
                    if constexpr (INT) {
                        #pragma unroll
                        for (int i = 0; i < 4; ++i) st.h[i] = (_Float16)fmaxf(accB[i], 0.f);
                    } else {
                        int gy = oy0 + (int)yB - 1, gx = ox0 + (int)xB - 1;
                        bool inimg = ((unsigned)gy < 512u) && ((unsigned)gx < 512u);
                        #pragma unroll
                        for (int i = 0; i < 4; ++i)
                            st.h[i] = inimg ? (_Float16)fmaxf(accB[i], 0.f) : (_Float16)0.f;
                    }
                    *(h4_t*)&h2w[(yB * 34 + xB) * 8 + wco] = st.v;
                }
            }
        }
        __syncthreads();

        // conv3: 16->1, 32x32 out — fixed 8 dual-tile iterations, fully unrolled
        {
            float b3v = b3[0];
            float gamma = sMLP[16], beta = sMLP[17];
            #pragma unroll
            for (int it = 0; it < 8; ++it) {
                int t = wave + 8 * it;
                int tB = t + 4;
                unsigned pA = (unsigned)(t * 16 + c15);
                unsigned pB = (unsigned)(tB * 16 + c15);
                unsigned yA = pA >> 5, xA = pA & 31u;
                unsigned yB = pB >> 5, xB = pB & 31u;
                int baseA = (int)(yA * 34 + xA) * 8;
                int baseB = (int)(yB * 34 + xB) * 8;
                f32x4 accA = {b3v, b3v, b3v, b3v};
                f32x4 accB = {b3v, b3v, b3v, b3v};
                #pragma unroll
                for (int c = 0; c < 5; ++c) {
                    H8 bfA, bfB;
                    bfA.v = *(const h8_t*)&h2r[baseA + off3[c]];
                    bfB.v = *(const h8_t*)&h2r[baseB + off3[c]];
                    accA = __builtin_amdgcn_mfma_f32_16x16x32_f16(wf3[c].v, bfA.v, accA, 0, 0, 0);
                    accB = __builtin_amdgcn_mfma_f32_16x16x32_f16(wf3[c].v, bfB.v, accB, 0, 0, 0);
                }
                if (l < 16) {  // lane holds D[co=0][pixel=l] in acc[0]
                    size_t oA = ((size_t)b << 18) + ((size_t)(oy0 + yA) << 9) + (ox0 + xA);
                    float o1 = fminf(fmaxf(base[oA] + gamma * accA[0] + beta, 0.f), 1.f);
                    out[oA] = o1;
                    size_t oB = ((size_t)b << 18) + ((size_t)(oy0 + yB) << 9) + (ox0 + xB);
                    float o2 = fminf(fmaxf(base[oB] + gamma * accB[0] + beta, 0.f), 1.f);
                    out[oB] = o2;
                }
            }
        }
    };

    if (interior) body(TrueT{});
    else          body(FalseT{});
}

extern "C" void kernel_launch(void* const* d_in, const int* in_sizes, int n_in,
                              void* d_out, int out_size, void* d_ws, size_t ws_size,
                              hipStream_t stream) {
    const float* noisy = (const float*)d_in[0];
    const float* base  = (const float*)d_in[1];
    const float* mem   = (const float*)d_in[2];
    const float* w1  = (const float*)d_in[3];
    const float* b1  = (const float*)d_in[4];
    const float* w2  = (const float*)d_in[5];
    const float* b2  = (const float*)d_in[6];
    const float* w3  = (const float*)d_in[7];
    const float* b3  = (const float*)d_in[8];
    const float* mw1 = (const float*)d_in[9];
    const float* mb1 = (const float*)d_in[10];
    const float* mw2 = (const float*)d_in[11];
    const float* mb2 = (const float*)d_in[12];

    double* wsd = (double*)d_ws;
    double* binacc = wsd;            // 288 doubles
    double* stats  = wsd + 288;      // 192 doubles
    float* out = (float*)d_out;

    hipLaunchKernelGGL(zero_ws, dim3(1), dim3(512), 0, stream, wsd);
    hipLaunchKernelGGL(fft_stats, dim3(3 * 32 * 128), dim3(512), 0, stream, noisy, base, mem, binacc, stats);
    hipLaunchKernelGGL(conv_fused, dim3(8192), dim3(256), 0, stream, noisy, base,
                       w1, b1, w2, b2, w3, b3, binacc, stats, mw1, mb1, mw2, mb2, out);
}

// Round 16
// 472.374 us; speedup vs baseline: 1.1098x; 1.1098x over previous
//
#include <hip/hip_runtime.h>
#include <stdint.h>

typedef _Float16 h8_t __attribute__((ext_vector_type(8)));
typedef _Float16 h4_t __attribute__((ext_vector_type(4)));
typedef float f32x4 __attribute__((ext_vector_type(4)));

union H8 { h8_t v; uint32_t u[4]; _Float16 h[8]; };
union H4 { h4_t v; uint32_t u[2]; _Float16 h[4]; };

struct TrueT  { static constexpr bool value = true;  };
struct FalseT { static constexpr bool value = false; };

// LDS row strides (f16 units), padded +8 f16 (bank de-phasing).
#define S1 584   // sH1: 36 rows, 576 written/row
#define S2 552   // sH2: 34 rows, 544 written/row

// ---------- workspace layout (doubles) ----------
// [0,288) binacc[3][32][3] ; [288,480) stats[3][32][2] (sum,sumsq)

__global__ void zero_ws(double* wsd) {
    int i = threadIdx.x;
    if (i < 480)
        __hip_atomic_store(&wsd[i], 0.0, __ATOMIC_RELAXED, __HIP_MEMORY_SCOPE_AGENT);
}

// ---------- FFT + global-stats: radix-4 DIT (512 = 2 x 4^4), 4 FFTs/block ----------
// 5 LDS passes + 5 barriers instead of 9 (radix-2). 128 threads per 512-pt FFT.
// Even/odd samples -> two 256-pt radix-4 sub-FFTs (base-4 digit-reversed input,
// in-place, natural-order output) -> radix-2 combine X(k)=E(k)+W^k O(k).
__global__ __launch_bounds__(512) void fft_stats(const float* __restrict__ noisy,
                                                 const float* __restrict__ base,
                                                 const float* __restrict__ mem,
                                                 double* __restrict__ binacc,
                                                 double* __restrict__ stats) {
    int bid = blockIdx.x;
    int tid = threadIdx.x;
    int fi  = tid >> 7;                    // fft id 0..3
    int w   = tid & 127;
    int grp = bid & 63;
    int b   = (bid >> 6) & 31;
    int iid = bid >> 11;                   // 0..2
    int rp  = grp * 4 + fi;                // row-pair 0..255
    const float* x = (iid == 0) ? noisy : (iid == 1) ? base : mem;
    const float2* rowA = (const float2*)(x + (((size_t)b << 9) + (rp << 1)) * 512);
    const float2* rowB = rowA + 256;

    __shared__ float re[2048], im[2048];
    __shared__ float2 tw[512];
    __shared__ float sbins[3];
    __shared__ float swsum[8], swsq[8];
    const int fb = fi << 9;

    // twiddle table: tw[j] = exp(-2*pi*i*j/512)
    {
        float ang = -6.2831853071795864769f * (float)tid * (1.f / 512.f);
        float sn, cs;
        __sincosf(ang, &sn, &cs);
        tw[tid] = make_float2(cs, sn);
    }

    // load 4 complex samples: x[n] = rowA[n] + i*rowB[n]; n = 2w,2w+1,2w+256,2w+257
    float2 a01 = rowA[w], a23 = rowA[w + 128];
    float2 b01 = rowB[w], b23 = rowB[w + 128];

    // base-4 digit reversal of 8-bit index
    auto rev4 = [](int n) {
        return ((n & 3) << 6) | (((n >> 2) & 3) << 4) | (((n >> 4) & 3) << 2) | ((n >> 6) & 3);
    };
    int r0 = rev4(w), r1 = rev4(w + 128);
    // even samples (m = w, w+128) -> E sub-FFT [0,256); odd -> O [256,512)
    re[fb + r0]       = a01.x; im[fb + r0]       = b01.x;
    re[fb + 256 + r0] = a01.y; im[fb + 256 + r0] = b01.y;
    re[fb + r1]       = a23.x; im[fb + r1]       = b23.x;
    re[fb + 256 + r1] = a23.y; im[fb + 256 + r1] = b23.y;

    // stats partials (8 values)
    float ps = a01.x + a01.y + a23.x + a23.y + b01.x + b01.y + b23.x + b23.y;
    float pq = a01.x*a01.x + a01.y*a01.y + a23.x*a23.x + a23.y*a23.y
             + b01.x*b01.x + b01.y*b01.y + b23.x*b23.x + b23.y*b23.y;
    #pragma unroll
    for (int off = 32; off > 0; off >>= 1) {
        ps += __shfl_down(ps, off);
        pq += __shfl_down(pq, off);
    }
    if ((tid & 63) == 0) { swsum[tid >> 6] = ps; swsq[tid >> 6] = pq; }
    if (tid < 3) sbins[tid] = 0.f;
    __syncthreads();

    // 4 radix-4 stages on the two 256-pt sub-FFTs (64 butterflies each)
    const int sub = w >> 6, bi = w & 63;
    const int sb = fb + sub * 256;
    #pragma unroll
    for (int s = 0; s < 4; ++s) {
        int h = 1 << (2 * s);
        int p = bi & (h - 1);
        int g4 = bi >> (2 * s);
        int i0 = sb + g4 * 4 * h + p;
        int es = p * (128 >> (2 * s));
        float2 w1 = tw[es], w2 = tw[2 * es], w3 = tw[3 * es];
        float x0r = re[i0],         x0i = im[i0];
        float a1r = re[i0 + h],     a1i = im[i0 + h];
        float a2r = re[i0 + 2*h],   a2i = im[i0 + 2*h];
        float a3r = re[i0 + 3*h],   a3i = im[i0 + 3*h];
        float x1r = a1r * w1.x - a1i * w1.y, x1i = a1r * w1.y + a1i * w1.x;
        float x2r = a2r * w2.x - a2i * w2.y, x2i = a2r * w2.y + a2i * w2.x;
        float x3r = a3r * w3.x - a3i * w3.y, x3i = a3r * w3.y + a3i * w3.x;
        float t0r = x0r + x2r, t0i = x0i + x2i;
        float t1r = x0r - x2r, t1i = x0i - x2i;
        float t2r = x1r + x3r, t2i = x1i + x3i;
        float t3r = x1r - x3r, t3i = x1i - x3i;
        re[i0]         = t0r + t2r; im[i0]         = t0i + t2i;   // X0
        re[i0 + h]     = t1r + t3i; im[i0 + h]     = t1i - t3r;   // X1 = t1 - i*t3
        re[i0 + 2*h]   = t0r - t2r; im[i0 + 2*h]   = t0i - t2i;   // X2
        re[i0 + 3*h]   = t1r - t3i; im[i0 + 3*h]   = t1i + t3r;   // X3 = t1 + i*t3
        __syncthreads();
    }

    // radix-2 combine: X(k) = E(k) + W^k O(k); X(k+256) = E(k) - W^k O(k)
    #pragma unroll
    for (int kk = 0; kk < 2; ++kk) {
        int k = w + kk * 128;
        float er = re[fb + k],       ei = im[fb + k];
        float orr = re[fb + 256 + k], oi = im[fb + 256 + k];
        float2 wv = tw[k];
        float tr = orr * wv.x - oi * wv.y, ti = orr * wv.y + oi * wv.x;
        re[fb + k]       = er + tr; im[fb + k]       = ei + ti;
        re[fb + 256 + k] = er - tr; im[fb + 256 + k] = ei - ti;
    }
    __syncthreads();

    // Hermitian extraction -> power -> 3 bins (f = w, w+128, and 256 for w==0)
    #pragma unroll
    for (int ii = 0; ii < 3; ++ii) {
        if (ii == 2 && w != 0) break;
        int f = (ii == 0) ? w : ((ii == 1) ? w + 128 : 256);
        int nf = (512 - f) & 511;
        float zr = re[fb + f], zi = im[fb + f];
        float yr = re[fb + nf], yi = im[fb + nf];
        float ar = 0.5f * (zr + yr), ai = 0.5f * (zi - yi);
        float br = 0.5f * (zi + yi), bi2 = -0.5f * (zr - yr);
        float pw = ar * ar + ai * ai + br * br + bi2 * bi2;
        int bin = (f < 85) ? 0 : ((f < 170) ? 1 : 2);
        atomicAdd(&sbins[bin], pw);
    }
    __syncthreads();
    if (tid < 3) atomicAdd(&binacc[(iid * 32 + b) * 3 + tid], (double)sbins[tid]);
    if (tid == 0) {
        float s8 = 0.f, q8 = 0.f;
        #pragma unroll
        for (int i = 0; i < 8; ++i) { s8 += swsum[i]; q8 += swsq[i]; }
        atomicAdd(&stats[(iid * 32 + b) * 2 + 0], (double)s8);
        atomicAdd(&stats[(iid * 32 + b) * 2 + 1], (double)q8);
    }
}

// ---------- fused MLP + MFMA conv1+conv2+conv3 + epilogue (R14 validated) ----------
__global__ __launch_bounds__(256, 2) void conv_fused(
    const float* __restrict__ noisy, const float* __restrict__ base,
    const float* __restrict__ w1, const float* __restrict__ b1,
    const float* __restrict__ w2, const float* __restrict__ b2,
    const float* __restrict__ w3, const float* __restrict__ b3,
    const double* __restrict__ binacc, const double* __restrict__ stats,
    const float* __restrict__ mw1, const float* __restrict__ mb1,
    const float* __restrict__ mw2, const float* __restrict__ mb2,
    float* __restrict__ out) {

    __shared__ _Float16 sH1[36 * S1 + 32];   // +pad (zeroed)
    __shared__ _Float16 sH2[34 * S2 + 32];
    __shared__ float sMLP[18];               // hid[16], gamma, beta
    _Float16* sIn = sH2;                     // overlay [38][40][2] = 3040 f16

    const int tid = threadIdx.x;
    const int bid = blockIdx.x;
    const int bx = bid & 15, by = (bid >> 4) & 15, b = bid >> 8;
    const int oy0 = by * 32, ox0 = bx * 32;
    const int l = tid & 63, wave = tid >> 6;
    const int g = l >> 4, c15 = l & 15;
    const int t1 = g >> 1, e8 = (g & 1) << 3;
    const bool interior = ((unsigned)(bx - 1) < 14u) && ((unsigned)(by - 1) < 14u);

    // ---- MLP phase A: threads 0..15 each compute one hidden unit ----
    if (tid < 16) {
        float feats[15];
        const double N = 262144.0;
        #pragma unroll
        for (int i = 0; i < 3; ++i) {
            const double* sp = &stats[(i * 32 + b) * 2];
            double s = __hip_atomic_load(&sp[0], __ATOMIC_RELAXED, __HIP_MEMORY_SCOPE_AGENT);
            double q = __hip_atomic_load(&sp[1], __ATOMIC_RELAXED, __HIP_MEMORY_SCOPE_AGENT);
            double mean = s / N;
            double var = (q - s * s / N) / (N - 1.0);
            feats[2 * i]     = (float)mean;
            feats[2 * i + 1] = sqrtf(fmaxf((float)var, 0.f));
        }
        const double cnt[3] = {85.0, 85.0, 87.0};
        #pragma unroll
        for (int i = 0; i < 3; ++i) {
            float fv[3]; float m = 0.f;
            #pragma unroll
            for (int k = 0; k < 3; ++k) {
                const double* bp = &binacc[(i * 32 + b) * 3 + k];
                double bv = __hip_atomic_load(bp, __ATOMIC_RELAXED, __HIP_MEMORY_SCOPE_AGENT);
                fv[k] = log1pf((float)(bv / (512.0 * cnt[k])));
                m += fv[k];
            }
            m = m * (1.f / 3.f);
            #pragma unroll
            for (int k = 0; k < 3; ++k) feats[6 + i * 3 + k] = fv[k] / (m + 1e-6f);
        }
        float a = mb1[tid];
        #pragma unroll
        for (int j = 0; j < 15; ++j) a += mw1[tid * 15 + j] * feats[j];
        sMLP[tid] = fmaxf(a, 0.f);
    }

    // ---- weight fragments (A operands), VGPR-resident ----
    H8 wf1; H8 wf2[5]; H8 wf3[5];
    #pragma unroll
    for (int i = 0; i < 8; ++i) {
        int k = 8 * g + i;
        float wv = 0.f;
        if (k < 18) wv = w1[c15 * 18 + (k & 1) * 9 + (k >> 1)];
        wf1.h[i] = (_Float16)wv;
    }
    #pragma unroll
    for (int c = 0; c < 4; ++c) {
        int tap = 2 * c + t1;
        #pragma unroll
        for (int i = 0; i < 8; ++i) {
            int ci = e8 + i;
            wf2[c].h[i] = (_Float16)w2[c15 * 144 + ci * 9 + tap];
            float w3v = 0.f;
            if (c15 == 0) w3v = w3[ci * 9 + tap];
            wf3[c].h[i] = (_Float16)w3v;
        }
    }
    #pragma unroll
    for (int i = 0; i < 8; ++i) {
        float w2v = 0.f, w3v = 0.f;
        if (g < 2) {
            int ci = (g << 3) + i;
            w2v = w2[c15 * 144 + ci * 9 + 8];
            if (c15 == 0) w3v = w3[ci * 9 + 8];
        }
        wf2[4].h[i] = (_Float16)w2v;
        wf3[4].h[i] = (_Float16)w3v;
    }

    // ---- precomputed per-lane LDS offsets (loop-invariant) ----
    int offIn[4], off2[5], off3[5];
    #pragma unroll
    for (int j = 0; j < 4; ++j) {
        int tap = 4 * g + j;
        int dy = (tap * 171) >> 9;
        int dx = tap - 3 * dy;
        offIn[j] = (tap < 9) ? ((dy * 40 + dx) * 2) : 0;   // invalid -> 0 (A rows are zero)
    }
    #pragma unroll
    for (int c = 0; c < 5; ++c) {
        int tap = (c < 4) ? (2 * c + t1) : 8;
        int dy = (tap * 171) >> 9;
        int dx = tap - 3 * dy;
        int ci0 = (c < 4) ? e8 : (g << 3);                 // g>=2 at c==4: A row zero, reads finite data
        off2[c] = dy * S1 + dx * 16 + ci0;
        off3[c] = dy * S2 + dx * 16 + ci0;
    }

    // ---- zero pads AND inter-row gaps (every garbage-read landing zone).
    //      sH2 gaps rows 0..4 lie inside the staged sIn overlay (finite). ----
    if (tid < 32) sH1[36 * S1 + tid] = (_Float16)0.f;
    else if (tid < 64) sH2[34 * S2 + (tid - 32)] = (_Float16)0.f;
    else if (tid < 100) {             // 36 sH1 row gaps
        int r = tid - 64;
        #pragma unroll
        for (int i = 0; i < 8; ++i) sH1[r * S1 + 576 + i] = (_Float16)0.f;
    } else if (tid < 129) {           // sH2 row gaps r=5..33
        int r = tid - 100 + 5;
        #pragma unroll
        for (int i = 0; i < 8; ++i) sH2[r * S2 + 544 + i] = (_Float16)0.f;
    }

    // ---- main body (templated on interior fast path) ----
    auto body = [&](auto tag) {
        constexpr bool INT = decltype(tag)::value;

        // stage input tile f16 [38][40][2] (halo 3)
        {
            const float* nB = noisy + ((size_t)b << 18);
            const float* bB = base + ((size_t)b << 18);
            for (int idx = tid; idx < 38 * 38; idx += 256) {
                unsigned iy = (unsigned)idx / 38u, ix = (unsigned)idx - iy * 38u;
                int gy = oy0 + (int)iy - 3, gx = ox0 + (int)ix - 3;
                float vn, vb;
                if constexpr (INT) {
                    int o = (gy << 9) + gx;
                    vn = nB[o]; vb = bB[o];
                } else {
                    vn = 0.f; vb = 0.f;
                    if ((unsigned)gy < 512u && (unsigned)gx < 512u) {
                        int o = (gy << 9) + gx;
                        vn = nB[o]; vb = bB[o];
                    }
                }
                union { uint32_t u; _Float16 h[2]; } pk;
                pk.h[0] = (_Float16)vn; pk.h[1] = (_Float16)vb;
                *(uint32_t*)&sIn[((int)iy * 40 + (int)ix) * 2] = pk.u;
            }
        }
        __syncthreads();

        // conv1: 2->16, 36x36 out — fixed 21 iterations, fully unrolled
        {
            f32x4 binit;
            #pragma unroll
            for (int i = 0; i < 4; ++i) binit[i] = b1[4 * g + i];
            #pragma unroll
            for (int it = 0; it < 21; ++it) {
                int t = wave + 4 * it;
                unsigned p = (unsigned)(t * 16 + c15);
                bool valid = p < 1296u;
                if (p > 1295u) p = 1295u;
                unsigned y1 = p / 36u, x1 = p - y1 * 36u;
                int baseIn = (y1 * 40 + x1) * 2;
                H8 bf;
                #pragma unroll
                for (int j = 0; j < 4; ++j)
                    bf.u[j] = *(const uint32_t*)&sIn[baseIn + offIn[j]];
                f32x4 acc = __builtin_amdgcn_mfma_f32_16x16x32_f16(wf1.v, bf.v, binit, 0, 0, 0);
                H4 st;
                if constexpr (INT) {
                    #pragma unroll
                    for (int i = 0; i < 4; ++i) st.h[i] = (_Float16)fmaxf(acc[i], 0.f);
                } else {
                    int gy = oy0 + (int)y1 - 2, gx = ox0 + (int)x1 - 2;
                    bool inimg = ((unsigned)gy < 512u) && ((unsigned)gx < 512u);
                    #pragma unroll
                    for (int i = 0; i < 4; ++i)
                        st.h[i] = inimg ? (_Float16)fmaxf(acc[i], 0.f) : (_Float16)0.f;
                }
                if (valid)
                    *(h4_t*)&sH1[y1 * S1 + x1 * 16 + 4 * g] = st.v;
            }
        }
        __syncthreads();

        // MLP phase B: thread 0 finishes gamma/beta
        if (tid == 0) {
            float h0 = mb2[0], h1 = mb2[1];
            #pragma unroll
            for (int j = 0; j < 16; ++j) { h0 += mw2[j] * sMLP[j]; h1 += mw2[16 + j] * sMLP[j]; }
            sMLP[16] = 1.f / (1.f + expf(-h0));
            sMLP[17] = 0.1f * tanhf(h1);
        }

        // conv2: 16->16, 34x34 out — fixed 10 dual-tile iterations, fully unrolled
        {
            f32x4 binit;
            #pragma unroll
            for (int i = 0; i < 4; ++i) binit[i] = b2[4 * g + i];
            #pragma unroll
            for (int it = 0; it < 10; ++it) {
                int t = wave + 8 * it;
                int tB = t + 4;
                unsigned pA = (unsigned)(t * 16 + c15);  if (pA > 1155u) pA = 1155u;
                unsigned pB = (unsigned)(tB * 16 + c15); if (pB > 1155u) pB = 1155u;
                unsigned yA = pA / 34u, xA = pA - yA * 34u;
                unsigned yB = pB / 34u, xB = pB - yB * 34u;
                int baseA = (int)(yA * S1 + xA * 16);
                int baseB = (int)(yB * S1 + xB * 16);
                f32x4 accA = binit, accB = binit;
                #pragma unroll
                for (int c = 0; c < 5; ++c) {
                    H8 bfA, bfB;
                    bfA.v = *(const h8_t*)&sH1[baseA + off2[c]];
                    bfB.v = *(const h8_t*)&sH1[baseB + off2[c]];
                    accA = __builtin_amdgcn_mfma_f32_16x16x32_f16(wf2[c].v, bfA.v, accA, 0, 0, 0);
                    accB = __builtin_amdgcn_mfma_f32_16x16x32_f16(wf2[c].v, bfB.v, accB, 0, 0, 0);
                }
                if ((unsigned)(t * 16 + c15) < 1156u) {
                    H4 st;
                    if constexpr (INT) {
                        #pragma unroll
                        for (int i = 0; i < 4; ++i) st.h[i] = (_Float16)fmaxf(accA[i], 0.f);
                    } else {
                        int gy = oy0 + (int)yA - 1, gx = ox0 + (int)xA - 1;
                        bool inimg = ((unsigned)gy < 512u) && ((unsigned)gx < 512u);
                        #pragma unroll
                        for (int i = 0; i < 4; ++i)
                            st.h[i] = inimg ? (_Float16)fmaxf(accA[i], 0.f) : (_Float16)0.f;
                    }
                    *(h4_t*)&sH2[yA * S2 + xA * 16 + 4 * g] = st.v;
                }
                if ((unsigned)(tB * 16 + c15) < 1156u) {
                    H4 st;
                    if constexpr (INT) {
                        #pragma unroll
                        for (int i = 0; i < 4; ++i) st.h[i] = (_Float16)fmaxf(accB[i], 0.f);
                    } else {
                        int gy = oy0 + (int)yB - 1, gx = ox0 + (int)xB - 1;
                        bool inimg = ((unsigned)gy < 512u) && ((unsigned)gx < 512u);
                        #pragma unroll
                        for (int i = 0; i < 4; ++i)
                            st.h[i] = inimg ? (_Float16)fmaxf(accB[i], 0.f) : (_Float16)0.f;
                    }
                    *(h4_t*)&sH2[yB * S2 + xB * 16 + 4 * g] = st.v;
                }
            }
        }
        __syncthreads();

        // conv3: 16->1, 32x32 out — fixed 8 dual-tile iterations, fully unrolled
        {
            float b3v = b3[0];
            float gamma = sMLP[16], beta = sMLP[17];
            #pragma unroll
            for (int it = 0; it < 8; ++it) {
                int t = wave + 8 * it;
                int tB = t + 4;
                unsigned pA = (unsigned)(t * 16 + c15);
                unsigned pB = (unsigned)(tB * 16 + c15);
                unsigned yA = pA >> 5, xA = pA & 31u;
                unsigned yB = pB >> 5, xB = pB & 31u;
                int baseA = (int)(yA * S2 + xA * 16);
                int baseB = (int)(yB * S2 + xB * 16);
                f32x4 accA = {b3v, b3v, b3v, b3v};
                f32x4 accB = {b3v, b3v, b3v, b3v};
                #pragma unroll
                for (int c = 0; c < 5; ++c) {
                    H8 bfA, bfB;
                    bfA.v = *(const h8_t*)&sH2[baseA + off3[c]];
                    bfB.v = *(const h8_t*)&sH2[baseB + off3[c]];
                    accA = __builtin_amdgcn_mfma_f32_16x16x32_f16(wf3[c].v, bfA.v, accA, 0, 0, 0);
                    accB = __builtin_amdgcn_mfma_f32_16x16x32_f16(wf3[c].v, bfB.v, accB, 0, 0, 0);
                }
                if (l < 16) {  // lane holds D[co=0][pixel=l] in acc[0]
                    size_t oA = ((size_t)b << 18) + ((size_t)(oy0 + yA) << 9) + (ox0 + xA);
                    float o1 = fminf(fmaxf(base[oA] + gamma * accA[0] + beta, 0.f), 1.f);
                    out[oA] = o1;
                    size_t oB = ((size_t)b << 18) + ((size_t)(oy0 + yB) << 9) + (ox0 + xB);
                    float o2 = fminf(fmaxf(base[oB] + gamma * accB[0] + beta, 0.f), 1.f);
                    out[oB] = o2;
                }
            }
        }
    };

    if (interior) body(TrueT{});
    else          body(FalseT{});
}

extern "C" void kernel_launch(void* const* d_in, const int* in_sizes, int n_in,
                              void* d_out, int out_size, void* d_ws, size_t ws_size,
                              hipStream_t stream) {
    const float* noisy = (const float*)d_in[0];
    const float* base  = (const float*)d_in[1];
    const float* mem   = (const float*)d_in[2];
    const float* w1  = (const float*)d_in[3];
    const float* b1  = (const float*)d_in[4];
    const float* w2  = (const float*)d_in[5];
    const float* b2  = (const float*)d_in[6];
    const float* w3  = (const float*)d_in[7];
    const float* b3  = (const float*)d_in[8];
    const float* mw1 = (const float*)d_in[9];
    const float* mb1 = (const float*)d_in[10];
    const float* mw2 = (const float*)d_in[11];
    const float* mb2 = (const float*)d_in[12];

    double* wsd = (double*)d_ws;
    double* binacc = wsd;            // 288 doubles
    double* stats  = wsd + 288;      // 192 doubles
    float* out = (float*)d_out;

    hipLaunchKernelGGL(zero_ws, dim3(1), dim3(512), 0, stream, wsd);
    hipLaunchKernelGGL(fft_stats, dim3(3 * 32 * 64), dim3(512), 0, stream, noisy, base, mem, binacc, stats);
    hipLaunchKernelGGL(conv_fused, dim3(8192), dim3(256), 0, stream, noisy, base,
                       w1, b1, w2, b2, w3, b3, binacc, stats, mw1, mb1, mw2, mb2, out);
}